// Round 1
// baseline (605.518 us; speedup 1.0000x reference)
//
#include <hip/hip_runtime.h>
#include <math.h>

#define TS 32
#define HALO 10
#define IN_TILE (TS + HALO)          // 42
#define SC1 0.0001f                  // 0.01^2
#define SC2 0.0009f                  // 0.03^2
#define PLANES 48                    // 16 batch * 3 channels

// ---------------- init: zero the per-level accumulators -------------------
__global__ void init_accum(float* acc) {
    if (threadIdx.x < 16) acc[threadIdx.x] = 0.0f;
}

// ---------------- fused per-level SSIM ------------------------------------
// One block = one 32x32 output tile of one (batch,channel) plane.
// Separable 11-tap Gaussian; all 5 windowed sums computed together.
__global__ __launch_bounds__(256) void ssim_level(
        const float* __restrict__ img1, const float* __restrict__ img2,
        const float* __restrict__ window, int H, int W,
        float* __restrict__ accum, int level)
{
    __shared__ float s1[IN_TILE][IN_TILE + 2];   // 42 x 44 (pad 2)
    __shared__ float s2[IN_TILE][IN_TILE + 2];
    __shared__ float hbuf[5][IN_TILE][TS + 4];   // 42 x 36 (pad 4, keeps 16B align)
    __shared__ float rbuf[8];

    const int tid = threadIdx.x;

    // 1D gaussian from the 2D window: w2 = outer(g,g) -> g[k] = w2[5][k]/sqrt(w2[5][5])
    float g[11];
    {
        float invg5 = 1.0f / sqrtf(window[60]);
        #pragma unroll
        for (int k = 0; k < 11; ++k) g[k] = window[55 + k] * invg5;
    }

    const int tx = blockIdx.x * TS;
    const int ty = blockIdx.y * TS;
    const size_t plane = (size_t)blockIdx.z * H * W;
    const float* p1 = img1 + plane;
    const float* p2 = img2 + plane;

    // Phase 1: load zero-padded halo tile (42x42) of both images
    for (int idx = tid; idx < IN_TILE * IN_TILE; idx += 256) {
        int r = idx / IN_TILE, c = idx - r * IN_TILE;
        int gy = ty + r - 5, gx = tx + c - 5;
        float a = 0.f, b = 0.f;
        if (gy >= 0 && gy < H && gx >= 0 && gx < W) {
            size_t o = (size_t)gy * W + gx;
            a = p1[o]; b = p2[o];
        }
        s1[r][c] = a;
        s2[r][c] = b;
    }
    __syncthreads();

    // Phase 2: horizontal pass over all 42 halo rows, 32 output columns.
    // 7 VALU + 2 LDS reads per tap for all five quantities.
    for (int idx = tid; idx < IN_TILE * TS; idx += 256) {
        int r = idx >> 5, c = idx & (TS - 1);
        float m1 = 0.f, m2 = 0.f, q11 = 0.f, q22 = 0.f, q12 = 0.f;
        #pragma unroll
        for (int k = 0; k < 11; ++k) {
            float a = s1[r][c + k], b = s2[r][c + k];
            float ga = g[k] * a, gb = g[k] * b;
            m1 += ga;
            m2 += gb;
            q11 = fmaf(ga, a, q11);
            q22 = fmaf(gb, b, q22);
            q12 = fmaf(ga, b, q12);
        }
        hbuf[0][r][c] = m1;  hbuf[1][r][c] = m2;
        hbuf[2][r][c] = q11; hbuf[3][r][c] = q22; hbuf[4][r][c] = q12;
    }
    __syncthreads();

    // Phase 3: vertical pass, 4 consecutive px per thread (float4 LDS reads)
    const int oy  = tid >> 3;          // 0..31
    const int ox0 = (tid & 7) << 2;    // 0,4,...,28
    float4 M1 = {0,0,0,0}, M2 = {0,0,0,0};
    float4 Q11 = {0,0,0,0}, Q22 = {0,0,0,0}, Q12 = {0,0,0,0};
    #pragma unroll
    for (int k = 0; k < 11; ++k) {
        float gk = g[k];
        #define ACC4(D, q) { \
            float4 v = *(const float4*)&hbuf[q][oy + k][ox0]; \
            D.x = fmaf(gk, v.x, D.x); D.y = fmaf(gk, v.y, D.y); \
            D.z = fmaf(gk, v.z, D.z); D.w = fmaf(gk, v.w, D.w); }
        ACC4(M1, 0) ACC4(M2, 1) ACC4(Q11, 2) ACC4(Q22, 3) ACC4(Q12, 4)
        #undef ACC4
    }

    // Epilogue: ssim & cs per pixel; one divide via combined reciprocal
    float ssum = 0.f, csum = 0.f;
    #define EPI(c) { \
        float mu1 = M1.c, mu2 = M2.c; \
        float mu1s = mu1 * mu1, mu2s = mu2 * mu2, mu12 = mu1 * mu2; \
        float v1 = Q11.c - mu1s, v2 = Q22.c - mu2s, v12 = Q12.c - mu12; \
        float n1 = 2.f * mu12 + SC1, n2 = 2.f * v12 + SC2; \
        float d1 = mu1s + mu2s + SC1, d2 = v1 + v2 + SC2; \
        float inv = 1.f / (d1 * d2); \
        csum += n2 * d1 * inv; \
        ssum += n1 * n2 * inv; }
    EPI(x) EPI(y) EPI(z) EPI(w)
    #undef EPI

    // Block reduction (wave64 shuffles -> LDS -> one atomic pair per block)
    #pragma unroll
    for (int off = 32; off > 0; off >>= 1) {
        ssum += __shfl_down(ssum, off);
        csum += __shfl_down(csum, off);
    }
    const int wid = tid >> 6, lane = tid & 63;
    if (lane == 0) { rbuf[wid * 2] = ssum; rbuf[wid * 2 + 1] = csum; }
    __syncthreads();
    if (tid == 0) {
        float S = rbuf[0] + rbuf[2] + rbuf[4] + rbuf[6];
        float C = rbuf[1] + rbuf[3] + rbuf[5] + rbuf[7];
        atomicAdd(&accum[2 * level],     S);
        atomicAdd(&accum[2 * level + 1], C);
    }
}

// ---------------- 2x2 average pool (both images at once) ------------------
__global__ __launch_bounds__(256) void down_kernel(
        const float* __restrict__ in1, const float* __restrict__ in2,
        float* __restrict__ out1, float* __restrict__ out2,
        int H2, int W2, int n)
{
    int i = blockIdx.x * 256 + threadIdx.x;
    if (i >= n) return;
    int x = i % W2;
    int t = i / W2;
    int y = t % H2;
    int p = t / H2;
    int W = W2 * 2;
    size_t base = ((size_t)p * (H2 * 2) + 2 * y) * W + 2 * x;
    float2 a = *(const float2*)(in1 + base);
    float2 b = *(const float2*)(in1 + base + W);
    out1[i] = 0.25f * ((a.x + a.y) + (b.x + b.y));
    float2 c = *(const float2*)(in2 + base);
    float2 d = *(const float2*)(in2 + base + W);
    out2[i] = 0.25f * ((c.x + c.y) + (d.x + d.y));
}

// ---------------- final weighted product ----------------------------------
__global__ void finalize_kernel(const float* __restrict__ accum, float* __restrict__ out) {
    const float w[5] = {0.0448f, 0.2856f, 0.3001f, 0.2363f, 0.1333f};
    float res = 1.0f;
    #pragma unroll
    for (int L = 0; L < 4; ++L) {
        float dim = (float)(512 >> L);
        float cnt = (float)PLANES * dim * dim;
        res *= powf(accum[2 * L + 1] / cnt, w[L]);
    }
    float cnt4 = (float)PLANES * 32.f * 32.f;
    res *= powf(accum[8] / cnt4, w[4]);   // mssim at last level
    out[0] = res;
}

// ---------------- launch ---------------------------------------------------
extern "C" void kernel_launch(void* const* d_in, const int* in_sizes, int n_in,
                              void* d_out, int out_size, void* d_ws, size_t ws_size,
                              hipStream_t stream) {
    const float* img1   = (const float*)d_in[0];
    const float* img2   = (const float*)d_in[1];
    const float* window = (const float*)d_in[2];
    float* out = (float*)d_out;
    float* ws  = (float*)d_ws;

    float* accum = ws;   // 16 floats
    // pyramid buffers (floats)
    const size_t S1 = (size_t)PLANES * 256 * 256;
    const size_t S2 = (size_t)PLANES * 128 * 128;
    const size_t S3 = (size_t)PLANES * 64 * 64;
    const size_t S4 = (size_t)PLANES * 32 * 32;
    float* l1a = ws + 16;      float* l1b = l1a + S1;
    float* l2a = l1b + S1;     float* l2b = l2a + S2;
    float* l3a = l2b + S2;     float* l3b = l3a + S3;
    float* l4a = l3b + S3;     float* l4b = l4a + S4;

    init_accum<<<1, 64, 0, stream>>>(accum);

    // level 0 (512)
    ssim_level<<<dim3(16, 16, PLANES), 256, 0, stream>>>(img1, img2, window, 512, 512, accum, 0);
    {
        int n = (int)S1;
        down_kernel<<<(n + 255) / 256, 256, 0, stream>>>(img1, img2, l1a, l1b, 256, 256, n);
    }
    // level 1 (256)
    ssim_level<<<dim3(8, 8, PLANES), 256, 0, stream>>>(l1a, l1b, window, 256, 256, accum, 1);
    {
        int n = (int)S2;
        down_kernel<<<(n + 255) / 256, 256, 0, stream>>>(l1a, l1b, l2a, l2b, 128, 128, n);
    }
    // level 2 (128)
    ssim_level<<<dim3(4, 4, PLANES), 256, 0, stream>>>(l2a, l2b, window, 128, 128, accum, 2);
    {
        int n = (int)S3;
        down_kernel<<<(n + 255) / 256, 256, 0, stream>>>(l2a, l2b, l3a, l3b, 64, 64, n);
    }
    // level 3 (64)
    ssim_level<<<dim3(2, 2, PLANES), 256, 0, stream>>>(l3a, l3b, window, 64, 64, accum, 3);
    {
        int n = (int)S4;
        down_kernel<<<(n + 255) / 256, 256, 0, stream>>>(l3a, l3b, l4a, l4b, 32, 32, n);
    }
    // level 4 (32)
    ssim_level<<<dim3(1, 1, PLANES), 256, 0, stream>>>(l4a, l4b, window, 32, 32, accum, 4);

    finalize_kernel<<<1, 1, 0, stream>>>(accum, out);
}

// Round 2
// 352.725 us; speedup vs baseline: 1.7167x; 1.7167x over previous
//
#include <hip/hip_runtime.h>
#include <math.h>

#define TW 16                // tile width  (output cols)
#define TH 32                // tile height (output rows)
#define HR (TH + 10)         // 42 halo rows for horizontal-pass outputs
#define SCOLS 28             // staged cols: tx-6 .. tx+21 (covers taps tx-5..tx+20)
#define HSTRIDE 20           // hbuf col stride (16 used + pad, keeps 16B align)
#define SC1 0.0001f
#define SC2 0.0009f
#define PLANES 48
#define NSLOT 64             // atomic spread slots per accumulator

// ---------------- init: zero the per-level accumulators -------------------
__global__ void init_accum(float* acc) {
    int i = blockIdx.x * 256 + threadIdx.x;
    if (i < 10 * NSLOT) acc[i] = 0.0f;
}

// ---------------- fused per-level SSIM + 2x2 pool -------------------------
// One block = 16x32 output tile of one (batch,channel) plane.
// LDS: s12 = interleaved {img1,img2} halo tile; hbuf = 5 horizontal sums.
__global__ __launch_bounds__(256, 5) void ssim_level(
        const float* __restrict__ img1, const float* __restrict__ img2,
        const float* __restrict__ window, int H, int W,
        float* __restrict__ accum, int level,
        float* __restrict__ pool1, float* __restrict__ pool2)
{
    __shared__ float s12[HR][SCOLS][2];      // 9408 B
    __shared__ float hbuf[5][HR][HSTRIDE];   // 16800 B
    __shared__ float rbuf[8];

    const int tid = threadIdx.x;

    // 1D gaussian from 2D window: g[k] = w2[5][k]/sqrt(w2[5][5])
    float g[11];
    {
        float invg5 = 1.0f / sqrtf(window[60]);
        #pragma unroll
        for (int k = 0; k < 11; ++k) g[k] = window[55 + k] * invg5;
    }

    const int tx = blockIdx.x * TW;
    const int ty = blockIdx.y * TH;
    const int plane = blockIdx.z;
    const float* p1 = img1 + (size_t)plane * H * W;
    const float* p2 = img2 + (size_t)plane * H * W;

    // ---- Phase 1: stage halo tile, both images interleaved ----
    // 42 rows x 14 float2-slots = 588 slots
    for (int s = tid; s < HR * (SCOLS / 2); s += 256) {
        int r = s / 14, j = s - r * 14;
        int gy = ty + r - 5;
        int gx = tx - 6 + 2 * j;
        float2 v1 = make_float2(0.f, 0.f), v2 = make_float2(0.f, 0.f);
        if ((unsigned)gy < (unsigned)H && (unsigned)gx < (unsigned)W) {
            size_t o = (size_t)gy * W + gx;
            v1 = *(const float2*)(p1 + o);
            v2 = *(const float2*)(p2 + o);
        }
        *(float4*)&s12[r][2 * j][0] = make_float4(v1.x, v2.x, v1.y, v2.y);
    }
    __syncthreads();

    // ---- Fused 2x2 avg-pool from the staged tile (interior rows/cols) ----
    if (level < 4 && tid < 128) {
        int pc = tid & 7;          // pooled col 0..7
        int pr = tid >> 3;         // pooled row 0..15
        int r  = 2 * pr + 5;       // s12 row of source row ty+2*pr
        int jj = 2 * pc + 6;       // s12 col of source col tx+2*pc
        float4 u0 = *(const float4*)&s12[r][jj][0];
        float4 u1 = *(const float4*)&s12[r + 1][jj][0];
        float pa = 0.25f * ((u0.x + u0.z) + (u1.x + u1.z));
        float pb = 0.25f * ((u0.y + u0.w) + (u1.y + u1.w));
        int W2 = W >> 1;
        size_t o = ((size_t)plane * (H >> 1) + ((ty >> 1) + pr)) * W2 + (tx >> 1) + pc;
        pool1[o] = pa;
        pool2[o] = pb;
    }

    // ---- Phase 2: horizontal 11-tap, 2 outputs per group, sliding taps ----
    // 42 rows x 8 col-pair groups = 336 groups
    for (int gi = tid; gi < HR * 8; gi += 256) {
        int r  = gi >> 3;
        int c0 = (gi & 7) << 1;
        float m1a = 0, m2a = 0, q11a = 0, q22a = 0, q12a = 0;
        float m1b = 0, m2b = 0, q11b = 0, q22b = 0, q12b = 0;
        #pragma unroll
        for (int k = 0; k < 12; ++k) {              // taps j = c0+1 .. c0+12
            float2 ab = *(const float2*)&s12[r][c0 + 1 + k][0];
            float a = ab.x, b = ab.y;
            if (k < 11) {
                float ga = g[k] * a, gb = g[k] * b;
                m1a += ga; m2a += gb;
                q11a = fmaf(ga, a, q11a);
                q22a = fmaf(gb, b, q22a);
                q12a = fmaf(ga, b, q12a);
            }
            if (k >= 1) {
                float gk = g[k - 1];
                float ga = gk * a, gb = gk * b;
                m1b += ga; m2b += gb;
                q11b = fmaf(ga, a, q11b);
                q22b = fmaf(gb, b, q22b);
                q12b = fmaf(ga, b, q12b);
            }
        }
        *(float2*)&hbuf[0][r][c0] = make_float2(m1a, m1b);
        *(float2*)&hbuf[1][r][c0] = make_float2(m2a, m2b);
        *(float2*)&hbuf[2][r][c0] = make_float2(q11a, q11b);
        *(float2*)&hbuf[3][r][c0] = make_float2(q22a, q22b);
        *(float2*)&hbuf[4][r][c0] = make_float2(q12a, q12b);
    }
    __syncthreads();

    // ---- Phase 3: vertical 11-tap, 4 stacked rows per thread + epilogue ----
    float ssum = 0.f, csum = 0.f;
    if (tid < 128) {
        int c  = tid & 15;              // output col 0..15
        int r0 = (tid >> 4) << 2;       // output rows r0..r0+3
        float M1[4]  = {0, 0, 0, 0}, M2[4]  = {0, 0, 0, 0};
        float Q11[4] = {0, 0, 0, 0}, Q22[4] = {0, 0, 0, 0}, Q12[4] = {0, 0, 0, 0};
        #pragma unroll
        for (int k = 0; k < 14; ++k) {  // h-rows r0+k; output j uses k = j..j+10
            float h0 = hbuf[0][r0 + k][c];
            float h1 = hbuf[1][r0 + k][c];
            float h2 = hbuf[2][r0 + k][c];
            float h3 = hbuf[3][r0 + k][c];
            float h4 = hbuf[4][r0 + k][c];
            #pragma unroll
            for (int j = 0; j < 4; ++j) {
                int t = k - j;
                if (t >= 0 && t < 11) {
                    float gk = g[t];
                    M1[j]  = fmaf(gk, h0, M1[j]);
                    M2[j]  = fmaf(gk, h1, M2[j]);
                    Q11[j] = fmaf(gk, h2, Q11[j]);
                    Q22[j] = fmaf(gk, h3, Q22[j]);
                    Q12[j] = fmaf(gk, h4, Q12[j]);
                }
            }
        }
        #pragma unroll
        for (int j = 0; j < 4; ++j) {
            float mu1 = M1[j], mu2 = M2[j];
            float mu1s = mu1 * mu1, mu2s = mu2 * mu2, mu12 = mu1 * mu2;
            float v1 = Q11[j] - mu1s, v2 = Q22[j] - mu2s, v12 = Q12[j] - mu12;
            float n1 = 2.f * mu12 + SC1, n2 = 2.f * v12 + SC2;
            float d1 = mu1s + mu2s + SC1, d2 = v1 + v2 + SC2;
            float inv = 1.f / (d1 * d2);
            csum += n2 * d1 * inv;
            ssum += n1 * n2 * inv;
        }
    }

    // ---- Block reduction -> one atomic pair per block (64-slot spread) ----
    #pragma unroll
    for (int off = 32; off; off >>= 1) {
        ssum += __shfl_down(ssum, off);
        csum += __shfl_down(csum, off);
    }
    const int wid = tid >> 6, lane = tid & 63;
    if (lane == 0) { rbuf[wid * 2] = ssum; rbuf[wid * 2 + 1] = csum; }
    __syncthreads();
    if (tid == 0) {
        float S = rbuf[0] + rbuf[2] + rbuf[4] + rbuf[6];
        float C = rbuf[1] + rbuf[3] + rbuf[5] + rbuf[7];
        int slot = (blockIdx.x + blockIdx.y * 7 + blockIdx.z * 13) & (NSLOT - 1);
        atomicAdd(&accum[(2 * level) * NSLOT + slot], S);
        atomicAdd(&accum[(2 * level + 1) * NSLOT + slot], C);
    }
}

// ---------------- final weighted product ----------------------------------
__global__ void finalize_kernel(const float* __restrict__ accum, float* __restrict__ out) {
    int t = threadIdx.x;   // 64 threads
    float sums[10];
    #pragma unroll
    for (int i = 0; i < 10; ++i) {
        float v = accum[i * NSLOT + t];
        #pragma unroll
        for (int off = 32; off; off >>= 1) v += __shfl_down(v, off);
        sums[i] = v;
    }
    if (t == 0) {
        const float w[5] = {0.0448f, 0.2856f, 0.3001f, 0.2363f, 0.1333f};
        float res = 1.f;
        #pragma unroll
        for (int L = 0; L < 4; ++L) {
            float dim = (float)(512 >> L);
            float cnt = (float)PLANES * dim * dim;
            res *= powf(sums[2 * L + 1] / cnt, w[L]);   // cs mean, levels 0..3
        }
        float cnt4 = (float)PLANES * 32.f * 32.f;
        res *= powf(sums[8] / cnt4, w[4]);              // ssim mean, level 4
        out[0] = res;
    }
}

// ---------------- launch ---------------------------------------------------
extern "C" void kernel_launch(void* const* d_in, const int* in_sizes, int n_in,
                              void* d_out, int out_size, void* d_ws, size_t ws_size,
                              hipStream_t stream) {
    const float* img1   = (const float*)d_in[0];
    const float* img2   = (const float*)d_in[1];
    const float* window = (const float*)d_in[2];
    float* out = (float*)d_out;
    float* ws  = (float*)d_ws;

    float* accum = ws;   // 640 floats
    const size_t S1 = (size_t)PLANES * 256 * 256;
    const size_t S2 = (size_t)PLANES * 128 * 128;
    const size_t S3 = (size_t)PLANES * 64 * 64;
    const size_t S4 = (size_t)PLANES * 32 * 32;
    float* l1a = ws + 1024;    float* l1b = l1a + S1;
    float* l2a = l1b + S1;     float* l2b = l2a + S2;
    float* l3a = l2b + S2;     float* l3b = l3a + S3;
    float* l4a = l3b + S3;     float* l4b = l4a + S4;

    init_accum<<<3, 256, 0, stream>>>(accum);

    ssim_level<<<dim3(512 / TW, 512 / TH, PLANES), 256, 0, stream>>>(
        img1, img2, window, 512, 512, accum, 0, l1a, l1b);
    ssim_level<<<dim3(256 / TW, 256 / TH, PLANES), 256, 0, stream>>>(
        l1a, l1b, window, 256, 256, accum, 1, l2a, l2b);
    ssim_level<<<dim3(128 / TW, 128 / TH, PLANES), 256, 0, stream>>>(
        l2a, l2b, window, 128, 128, accum, 2, l3a, l3b);
    ssim_level<<<dim3(64 / TW, 64 / TH, PLANES), 256, 0, stream>>>(
        l3a, l3b, window, 64, 64, accum, 3, l4a, l4b);
    ssim_level<<<dim3(32 / TW, 32 / TH, PLANES), 256, 0, stream>>>(
        l4a, l4b, window, 32, 32, accum, 4, nullptr, nullptr);

    finalize_kernel<<<1, 64, 0, stream>>>(accum, out);
}